// Round 19
// baseline (184.497 us; speedup 1.0000x reference)
//
#include <hip/hip_runtime.h>
#include <hip/hip_bf16.h>

using short8 = __attribute__((ext_vector_type(8))) short;
using f32x4  = __attribute__((ext_vector_type(4))) float;

constexpr int Bn = 16, Cc = 16, Hh = 256, Ww = 256;
constexpr int NOISEC = 4, HID = 128, CDIM = 64;
constexpr unsigned NTOT = (unsigned)Bn * NOISEC * Hh * Ww;   // 4194304
constexpr unsigned HALF = NTOT / 2;                          // 2097152

// ---------------- threefry2x32 (JAX-compatible, 20 rounds) ----------------
__host__ __device__ __forceinline__ unsigned rotl(unsigned x, int d) {
    return (x << d) | (x >> (32 - d));
}

__host__ __device__ __forceinline__ void tf2x32(unsigned k0, unsigned k1,
                                                unsigned c0, unsigned c1,
                                                unsigned& o0, unsigned& o1) {
    unsigned k2 = k0 ^ k1 ^ 0x1BD11BDAu;
    unsigned x0 = c0 + k0, x1 = c1 + k1;
    x0 += x1; x1 = rotl(x1, 13); x1 ^= x0;
    x0 += x1; x1 = rotl(x1, 15); x1 ^= x0;
    x0 += x1; x1 = rotl(x1, 26); x1 ^= x0;
    x0 += x1; x1 = rotl(x1, 6);  x1 ^= x0;
    x0 += k1; x1 += k2 + 1u;
    x0 += x1; x1 = rotl(x1, 17); x1 ^= x0;
    x0 += x1; x1 = rotl(x1, 29); x1 ^= x0;
    x0 += x1; x1 = rotl(x1, 16); x1 ^= x0;
    x0 += x1; x1 = rotl(x1, 24); x1 ^= x0;
    x0 += k2; x1 += k0 + 2u;
    x0 += x1; x1 = rotl(x1, 13); x1 ^= x0;
    x0 += x1; x1 = rotl(x1, 15); x1 ^= x0;
    x0 += x1; x1 = rotl(x1, 26); x1 ^= x0;
    x0 += x1; x1 = rotl(x1, 6);  x1 ^= x0;
    x0 += k0; x1 += k1 + 3u;
    x0 += x1; x1 = rotl(x1, 17); x1 ^= x0;
    x0 += x1; x1 = rotl(x1, 29); x1 ^= x0;
    x0 += x1; x1 = rotl(x1, 16); x1 ^= x0;
    x0 += x1; x1 = rotl(x1, 24); x1 ^= x0;
    x0 += k1; x1 += k2 + 4u;
    x0 += x1; x1 = rotl(x1, 13); x1 ^= x0;
    x0 += x1; x1 = rotl(x1, 15); x1 ^= x0;
    x0 += x1; x1 = rotl(x1, 26); x1 ^= x0;
    x0 += x1; x1 = rotl(x1, 6);  x1 ^= x0;
    x0 += k2; x1 += k0 + 5u;
    o0 = x0; o1 = x1;
}

// XLA's f32 erf_inv (Giles polynomial)
__device__ __forceinline__ float erfinv_f(float x) {
    float w = -log1pf(-x * x);
    float p;
    if (w < 5.0f) {
        w = w - 2.5f;
        p = 2.81022636e-08f;
        p = fmaf(p, w, 3.43273939e-07f);
        p = fmaf(p, w, -3.5233877e-06f);
        p = fmaf(p, w, -4.39150654e-06f);
        p = fmaf(p, w, 0.00021858087f);
        p = fmaf(p, w, -0.00125372503f);
        p = fmaf(p, w, -0.00417768164f);
        p = fmaf(p, w, 0.246640727f);
        p = fmaf(p, w, 1.50140941f);
    } else {
        w = sqrtf(w) - 3.0f;
        p = -0.000200214257f;
        p = fmaf(p, w, 0.000100950558f);
        p = fmaf(p, w, 0.00134934322f);
        p = fmaf(p, w, -0.00367342844f);
        p = fmaf(p, w, 0.00573950773f);
        p = fmaf(p, w, -0.0076224613f);
        p = fmaf(p, w, 0.00943887047f);
        p = fmaf(p, w, 1.00167406f);
        p = fmaf(p, w, 2.83297682f);
    }
    return p * x;
}

__device__ __forceinline__ float noise_val(unsigned j, unsigned fk0, unsigned fk1) {
    unsigned i = (j < HALF) ? j : (j - HALF);
    unsigned o0, o1;
    tf2x32(fk0, fk1, i, i + HALF, o0, o1);
    unsigned bits = (j < HALF) ? o0 : o1;
    unsigned fb = (bits >> 9) | 0x3F800000u;
    float f = __uint_as_float(fb) - 1.0f;
    const float lo = -0.99999994f;
    float u = f * 2.0f + lo;
    u = fmaxf(lo, u);
    return 1.4142135381698608f * erfinv_f(u);
}

// f32 -> bf16 round-to-nearest-even
__device__ __forceinline__ ushort f2bf(float f) {
    unsigned u = __float_as_uint(f);
    unsigned r = (u + 0x7FFFu + ((u >> 16) & 1u)) >> 16;
    return (ushort)r;
}

// pack two f32 -> two bf16 in one dword (RNE), gfx950
__device__ __forceinline__ unsigned cvtpk(float lo, float hi) {
    unsigned r;
    asm volatile("v_cvt_pk_bf16_f32 %0, %1, %2" : "=v"(r) : "v"(lo), "v"(hi));
    return r;
}

// full-row swizzle: folds row bits 0-3 AND 4-7 into the 16B-chunk index.
__device__ __forceinline__ unsigned rsw(int row) {
    return ((unsigned)((row ^ (row >> 4)) & 15)) << 4;
}

// ---------------- FiLM params: film[b][{g1,b1,g2,b2}][HID] ----------------
__global__ void film_kernel(const int* __restrict__ cond,
                            const float* __restrict__ embed,
                            const float* __restrict__ f1w, const float* __restrict__ f1b,
                            const float* __restrict__ f2w, const float* __restrict__ f2b,
                            float* __restrict__ film) {
    int b = blockIdx.x;
    int j = threadIdx.x;  // 0..255
    __shared__ float emb[CDIM];
    if (j < CDIM) emb[j] = embed[(size_t)cond[b] * CDIM + j];
    __syncthreads();
    float a1 = f1b[j], a2 = f2b[j];
    for (int c = 0; c < CDIM; ++c) {
        float e = emb[c];
        a1 += e * f1w[c * 2 * HID + j];
        a2 += e * f2w[c * 2 * HID + j];
    }
    int which = j >> 7;
    int idx = j & 127;
    float* fb_ = film + (size_t)b * 4 * HID;
    fb_[which * HID + idx] = a1;
    fb_[(2 + which) * HID + idx] = a2;
}

// ------------- weights -> bf16, transposed to [out][in] (linear) -------------
__global__ void prep_weights(const float* __restrict__ fc1w,
                             const float* __restrict__ fc2w,
                             const float* __restrict__ fc3w,
                             ushort* __restrict__ w1t, ushort* __restrict__ w2t,
                             ushort* __restrict__ w3t) {
    int i = blockIdx.x * 256 + threadIdx.x;
    if (i < 128 * 64) {                       // w1t[j][k], k padded 52->64
        int j = i >> 6, k = i & 63;
        w1t[i] = (k < 52) ? f2bf(fc1w[k * HID + j]) : (ushort)0;
    } else if (i < 8192 + 128 * 128) {        // w2t[j][k]
        int m = i - 8192;
        int j = m >> 7, k = m & 127;
        w2t[m] = f2bf(fc2w[k * HID + j]);
    } else if (i < 8192 + 16384 + 16 * 128) { // w3t[c][k]
        int m = i - 24576;
        int c = m >> 7, k = m & 127;
        w3t[m] = f2bf(fc3w[k * Cc + c]);
    }
}

// ------- main MFMA kernel: 1 block = 1 image row; BARRIER-FREE wave bands -------
// 256 threads (4 waves). Wave w owns px band 64w..64w+63 for EVERYTHING:
// feats thread = (ch-quad cq=lane>>4, px-quad 64w+4*(lane&15)); halo via in-wave
// shfl, seam lanes (pi=0/15) load 3 scalars/ch from global. GEMM reads only the
// wave's own rows -> no __syncthreads; s_waitcnt lgkmcnt(0) orders LDS in-wave.
// Waves drift phase-independently (m114 overlap); setprio(1) wraps MFMA (T5).
// + XCD swizzle (R18), rsw LDS swizzle (R13), feats load-first reorder (R16).
__global__ __launch_bounds__(256, 2)
void nca_mfma(const float* __restrict__ x,
              const ushort* __restrict__ w1t, const ushort* __restrict__ w2t,
              const ushort* __restrict__ w3t,
              const float* __restrict__ fc1b, const float* __restrict__ fc2b,
              const float* __restrict__ fc3b, const float* __restrict__ film,
              float* __restrict__ out, unsigned fk0, unsigned fk1) {
    __shared__ __align__(16) unsigned char Hb[256 * 256];   // 64 KB

    // XCD-aware remap (R18): each XCD gets a contiguous 512-row span.
    const int P = blockIdx.x;
    const int blk = ((P & 7) << 9) | (P >> 3);
    const int b = blk >> 8, y = blk & 255;
    const int t = threadIdx.x;
    const int lane = t & 63, wv = t >> 6;
    const float* xb = x + (size_t)b * Cc * Hh * Ww;

    // ---------- feats phase: wave-private band; thread = (cq, pi) ----------
    {
        const int pi = lane & 15;          // px-quad within wave band
        const int cq = lane >> 4;          // channel quad 0..3
        const int px0 = wv * 64 + pi * 4;  // first px of this thread's quad
        const bool okm = (y > 0), okp = (y < Hh - 1);
        const float4 fz = {0.f, 0.f, 0.f, 0.f};

        // (1) issue all 12 vector loads up front
        float4 RM[4], RC[4], RP[4];
        #pragma unroll
        for (int cc = 0; cc < 4; ++cc) {
            const int c = cq * 4 + cc;
            const float* base = xb + ((size_t)c * Hh + (size_t)y) * Ww + px0;
            RM[cc] = okm ? *(const float4*)(base - Ww) : fz;
            RC[cc] = *(const float4*)(base);
            RP[cc] = okp ? *(const float4*)(base + Ww) : fz;
        }

        // (2) threefry + erfinv while loads fly (pure VALU)
        ushort nzs[4];
        {
            unsigned nbase = (((unsigned)(b * NOISEC + cq) * Hh + (unsigned)y) * Ww)
                             + (unsigned)px0;
            #pragma unroll
            for (int i = 0; i < 4; ++i)
                nzs[i] = f2bf(noise_val(nbase + (unsigned)i, fk0, fk1));
        }
        #pragma unroll
        for (int i = 0; i < 4; ++i) {
            const int row = px0 + i;
            const unsigned sw = rsw(row);
            *(ushort*)(Hb + row * 256 + (((224u ^ sw) + 2u * cq))) = nzs[i];
        }
        if (cq == 0) {
            #pragma unroll
            for (int i = 0; i < 4; ++i) {
                const int row = px0 + i;
                const unsigned sw = rsw(row);
                *(uint2*)(Hb + row * 256 + ((232u & 15u) + (224u ^ sw))) = (uint2){0u, 0u};
                *(uint4*)(Hb + row * 256 + (240u ^ sw)) = (uint4){0u, 0u, 0u, 0u};
            }
        }

        // (3) consume: in-wave shfl halo (seam lanes load from global), sobel, pack
        float vx[4][4], vgx[4][4], vgy[4][4];
        #pragma unroll
        for (int cc = 0; cc < 4; ++cc) {
            const int c = cq * 4 + cc;
            const float* base = xb + ((size_t)c * Hh + (size_t)y) * Ww + px0;
            float4 rm = RM[cc], rc = RC[cc], rp = RP[cc];
            float mL = __shfl_up(rm.w, 1),  mR = __shfl_down(rm.x, 1);
            float cL = __shfl_up(rc.w, 1),  cR = __shfl_down(rc.x, 1);
            float pL = __shfl_up(rp.w, 1),  pR = __shfl_down(rp.x, 1);
            if (pi == 0) {
                if (px0 > 0) {            // band seam: left neighbor from global
                    mL = okm ? base[-Ww - 1] : 0.f;
                    cL = base[-1];
                    pL = okp ? base[Ww - 1] : 0.f;
                } else { mL = 0.f; cL = 0.f; pL = 0.f; }   // image edge
            }
            if (pi == 15) {
                if (px0 + 4 < Ww) {       // band seam: right neighbor from global
                    mR = okm ? base[-Ww + 4] : 0.f;
                    cR = base[4];
                    pR = okp ? base[Ww + 4] : 0.f;
                } else { mR = 0.f; cR = 0.f; pR = 0.f; }   // image edge
            }
            float am[6] = {mL, rm.x, rm.y, rm.z, rm.w, mR};
            float ac[6] = {cL, rc.x, rc.y, rc.z, rc.w, cR};
            float ap[6] = {pL, rp.x, rp.y, rp.z, rp.w, pR};
            #pragma unroll
            for (int i = 0; i < 4; ++i) {
                float a0 = am[i], a1 = am[i + 1], a2 = am[i + 2];
                float b0 = ac[i], b1 = ac[i + 1], b2 = ac[i + 2];
                float e0 = ap[i], e1 = ap[i + 1], e2 = ap[i + 2];
                vx[cc][i]  = b1;
                vgx[cc][i] = (a2 + 2.f * b2 + e2) - (a0 + 2.f * b0 + e0);
                vgy[cc][i] = (e0 + 2.f * e1 + e2) - (a0 + 2.f * a1 + a2);
            }
        }
        #pragma unroll
        for (int i = 0; i < 4; ++i) {
            const int row = px0 + i;
            const unsigned sw = rsw(row);
            unsigned char* rowp = Hb + row * 256;
            uint2 u;
            u.x = cvtpk(vx[0][i], vx[1][i]);  u.y = cvtpk(vx[2][i], vx[3][i]);
            *(uint2*)(rowp + ((128u + 8u * cq) ^ sw)) = u;
            u.x = cvtpk(vgx[0][i], vgx[1][i]); u.y = cvtpk(vgx[2][i], vgx[3][i]);
            *(uint2*)(rowp + ((160u + 8u * cq) ^ sw)) = u;
            u.x = cvtpk(vgy[0][i], vgy[1][i]); u.y = cvtpk(vgy[2][i], vgy[3][i]);
            *(uint2*)(rowp + ((192u + 8u * cq) ^ sw)) = u;
        }
    }
    // No __syncthreads: each wave reads only rows it wrote. In-wave LDS ordering:
    asm volatile("s_waitcnt lgkmcnt(0)" ::: "memory");

    // ---------- GEMM phase: wave wv owns tiles 4wv..4wv+3 (its own band) ----------
    const int q = lane >> 4, p = lane & 15;
    const int nt0 = wv * 4;

    unsigned swn[4];
    #pragma unroll
    for (int n = 0; n < 4; ++n) swn[n] = rsw((nt0 + n) * 16 + p);

    f32x4 acc[8][4];

    // ---------- GEMM1: h1^T[128][64px] = W1[128][64] x feats^T ----------
    #pragma unroll
    for (int m = 0; m < 8; ++m)
        #pragma unroll
        for (int n = 0; n < 4; ++n) acc[m][n] = (f32x4){0.f, 0.f, 0.f, 0.f};

    __builtin_amdgcn_s_setprio(1);
    #pragma unroll
    for (int ks = 0; ks < 2; ++ks) {
        short8 Bf[4];
        #pragma unroll
        for (int n = 0; n < 4; ++n) {
            int row = (nt0 + n) * 16 + p;
            Bf[n] = *(const short8*)(Hb + row * 256 +
                                     (((unsigned)(128 + ks * 64 + q * 16)) ^ swn[n]));
        }
        #pragma unroll
        for (int m = 0; m < 8; ++m) {
            short8 Af = *(const short8*)((const unsigned char*)w1t +
                                         (m * 16 + p) * 128 + ks * 64 + q * 16);
            #pragma unroll
            for (int n = 0; n < 4; ++n)
                acc[m][n] = __builtin_amdgcn_mfma_f32_16x16x32_bf16(Af, Bf[n], acc[m][n], 0, 0, 0);
        }
    }
    __builtin_amdgcn_s_setprio(0);
    // epilogue 1: bias, relu, FiLM1, pack -> h rows (own band)
    const float* flm = film + (size_t)b * 4 * HID;
    #pragma unroll
    for (int m = 0; m < 8; ++m) {
        int j0 = m * 16 + q * 4;
        float4 cb = *(const float4*)(fc1b + j0);
        float4 G  = *(const float4*)(flm + 0 * HID + j0);
        float4 Be = *(const float4*)(flm + 1 * HID + j0);
        #pragma unroll
        for (int n = 0; n < 4; ++n) {
            int row = (nt0 + n) * 16 + p;
            f32x4 a = acc[m][n];
            float v0 = G.x * fmaxf(a[0] + cb.x, 0.f) + Be.x;
            float v1 = G.y * fmaxf(a[1] + cb.y, 0.f) + Be.y;
            float v2 = G.z * fmaxf(a[2] + cb.z, 0.f) + Be.z;
            float v3 = G.w * fmaxf(a[3] + cb.w, 0.f) + Be.w;
            uint2 u2; u2.x = cvtpk(v0, v1); u2.y = cvtpk(v2, v3);
            *(uint2*)(Hb + row * 256 + (((unsigned)(m * 32 + q * 8)) ^ swn[n])) = u2;
        }
    }

    // ---------- GEMM2: h2^T[128][64px] = W2[128][128] x h1^T ----------
    #pragma unroll
    for (int m = 0; m < 8; ++m)
        #pragma unroll
        for (int n = 0; n < 4; ++n) acc[m][n] = (f32x4){0.f, 0.f, 0.f, 0.f};

    __builtin_amdgcn_s_setprio(1);
    #pragma unroll
    for (int ks = 0; ks < 4; ++ks) {
        short8 Bf[4];
        #pragma unroll
        for (int n = 0; n < 4; ++n) {
            int row = (nt0 + n) * 16 + p;
            Bf[n] = *(const short8*)(Hb + row * 256 +
                                     (((unsigned)(ks * 64 + q * 16)) ^ swn[n]));
        }
        #pragma unroll
        for (int m = 0; m < 8; ++m) {
            short8 Af = *(const short8*)((const unsigned char*)w2t +
                                         (m * 16 + p) * 256 + ks * 64 + q * 16);
            #pragma unroll
            for (int n = 0; n < 4; ++n)
                acc[m][n] = __builtin_amdgcn_mfma_f32_16x16x32_bf16(Af, Bf[n], acc[m][n], 0, 0, 0);
        }
    }
    __builtin_amdgcn_s_setprio(0);
    // epilogue 2: bias, relu, FiLM2, pack -> h rows (in place, own band)
    #pragma unroll
    for (int m = 0; m < 8; ++m) {
        int j0 = m * 16 + q * 4;
        float4 cb = *(const float4*)(fc2b + j0);
        float4 G  = *(const float4*)(flm + 2 * HID + j0);
        float4 Be = *(const float4*)(flm + 3 * HID + j0);
        #pragma unroll
        for (int n = 0; n < 4; ++n) {
            int row = (nt0 + n) * 16 + p;
            f32x4 a = acc[m][n];
            float v0 = G.x * fmaxf(a[0] + cb.x, 0.f) + Be.x;
            float v1 = G.y * fmaxf(a[1] + cb.y, 0.f) + Be.y;
            float v2 = G.z * fmaxf(a[2] + cb.z, 0.f) + Be.z;
            float v3 = G.w * fmaxf(a[3] + cb.w, 0.f) + Be.w;
            uint2 u2; u2.x = cvtpk(v0, v1); u2.y = cvtpk(v2, v3);
            *(uint2*)(Hb + row * 256 + (((unsigned)(m * 32 + q * 8)) ^ swn[n])) = u2;
        }
    }

    // ---------- prefetch ep3's xb reloads (hide under GEMM3) ----------
    float xpre[4][4];
    #pragma unroll
    for (int n = 0; n < 4; ++n) {
        int px = (nt0 + n) * 16 + p;
        #pragma unroll
        for (int r = 0; r < 4; ++r) {
            int c = q * 4 + r;
            xpre[n][r] = xb[(size_t)c * Hh * Ww + (size_t)y * Ww + px];
        }
    }

    // ---------- GEMM3: dx^T[16][64px] = W3[16][128] x h2^T ----------
    f32x4 a3[4];
    #pragma unroll
    for (int n = 0; n < 4; ++n) a3[n] = (f32x4){0.f, 0.f, 0.f, 0.f};

    __builtin_amdgcn_s_setprio(1);
    #pragma unroll
    for (int ks = 0; ks < 4; ++ks) {
        short8 Af = *(const short8*)((const unsigned char*)w3t +
                                     p * 256 + ks * 64 + q * 16);
        #pragma unroll
        for (int n = 0; n < 4; ++n) {
            int row = (nt0 + n) * 16 + p;
            short8 Bf = *(const short8*)(Hb + row * 256 +
                                         (((unsigned)(ks * 64 + q * 16)) ^ swn[n]));
            a3[n] = __builtin_amdgcn_mfma_f32_16x16x32_bf16(Af, Bf, a3[n], 0, 0, 0);
        }
    }
    __builtin_amdgcn_s_setprio(0);
    // epilogue 3: bias, clip, Euler step (x values prefetched)
    {
        float4 c3 = *(const float4*)(fc3b + q * 4);
        float c3a[4] = {c3.x, c3.y, c3.z, c3.w};
        float* ob = out + (size_t)b * Cc * Hh * Ww;
        #pragma unroll
        for (int n = 0; n < 4; ++n) {
            int px = (nt0 + n) * 16 + p;
            #pragma unroll
            for (int r = 0; r < 4; ++r) {
                int c = q * 4 + r;
                float dx = a3[n][r] + c3a[r];
                dx = fminf(fmaxf(dx, -10.0f), 10.0f);
                size_t off = (size_t)c * Hh * Ww + (size_t)y * Ww + px;
                ob[off] = xpre[n][r] + 0.1f * dx;
            }
        }
    }
}

extern "C" void kernel_launch(void* const* d_in, const int* in_sizes, int n_in,
                              void* d_out, int out_size, void* d_ws, size_t ws_size,
                              hipStream_t stream) {
    const float* x     = (const float*)d_in[0];
    const int*   cond  = (const int*)d_in[1];
    const float* embed = (const float*)d_in[2];
    const float* f1w   = (const float*)d_in[3];
    const float* f1b   = (const float*)d_in[4];
    const float* f2w   = (const float*)d_in[5];
    const float* f2b   = (const float*)d_in[6];
    const float* fc1w  = (const float*)d_in[7];
    const float* fc1b  = (const float*)d_in[8];
    const float* fc2w  = (const float*)d_in[9];
    const float* fc2b  = (const float*)d_in[10];
    const float* fc3w  = (const float*)d_in[11];
    const float* fc3b  = (const float*)d_in[12];
    float* out = (float*)d_out;

    // ws layout: film f32 [16][4][128] (32 KB) | w1t bf16 (16 KB) | w2t (32 KB) | w3t (4 KB)
    float*  film = (float*)d_ws;
    ushort* w1t  = (ushort*)((char*)d_ws + 32768);
    ushort* w2t  = (ushort*)((char*)d_ws + 32768 + 16384);
    ushort* w3t  = (ushort*)((char*)d_ws + 32768 + 16384 + 32768);

    unsigned fk0, fk1;
    tf2x32(0u, 1u, 0u, 0u, fk0, fk1);   // fold_in(key(1), 0)

    film_kernel<<<Bn, 256, 0, stream>>>(cond, embed, f1w, f1b, f2w, f2b, film);
    prep_weights<<<(8192 + 16384 + 2048 + 255) / 256, 256, 0, stream>>>(
        fc1w, fc2w, fc3w, w1t, w2t, w3t);
    nca_mfma<<<Bn * Hh, 256, 0, stream>>>(x, w1t, w2t, w3t, fc1b, fc2b, fc3b,
                                          film, out, fk0, fk1);
}

// Round 20
// 182.458 us; speedup vs baseline: 1.0112x; 1.0112x over previous
//
#include <hip/hip_runtime.h>
#include <hip/hip_bf16.h>

using short8 = __attribute__((ext_vector_type(8))) short;
using f32x4  = __attribute__((ext_vector_type(4))) float;

constexpr int Bn = 16, Cc = 16, Hh = 256, Ww = 256;
constexpr int NOISEC = 4, HID = 128, CDIM = 64;
constexpr unsigned NTOT = (unsigned)Bn * NOISEC * Hh * Ww;   // 4194304
constexpr unsigned HALF = NTOT / 2;                          // 2097152

// ---------------- threefry2x32 (JAX-compatible, 20 rounds) ----------------
__host__ __device__ __forceinline__ unsigned rotl(unsigned x, int d) {
    return (x << d) | (x >> (32 - d));
}

__host__ __device__ __forceinline__ void tf2x32(unsigned k0, unsigned k1,
                                                unsigned c0, unsigned c1,
                                                unsigned& o0, unsigned& o1) {
    unsigned k2 = k0 ^ k1 ^ 0x1BD11BDAu;
    unsigned x0 = c0 + k0, x1 = c1 + k1;
    x0 += x1; x1 = rotl(x1, 13); x1 ^= x0;
    x0 += x1; x1 = rotl(x1, 15); x1 ^= x0;
    x0 += x1; x1 = rotl(x1, 26); x1 ^= x0;
    x0 += x1; x1 = rotl(x1, 6);  x1 ^= x0;
    x0 += k1; x1 += k2 + 1u;
    x0 += x1; x1 = rotl(x1, 17); x1 ^= x0;
    x0 += x1; x1 = rotl(x1, 29); x1 ^= x0;
    x0 += x1; x1 = rotl(x1, 16); x1 ^= x0;
    x0 += x1; x1 = rotl(x1, 24); x1 ^= x0;
    x0 += k2; x1 += k0 + 2u;
    x0 += x1; x1 = rotl(x1, 13); x1 ^= x0;
    x0 += x1; x1 = rotl(x1, 15); x1 ^= x0;
    x0 += x1; x1 = rotl(x1, 26); x1 ^= x0;
    x0 += x1; x1 = rotl(x1, 6);  x1 ^= x0;
    x0 += k0; x1 += k1 + 3u;
    x0 += x1; x1 = rotl(x1, 17); x1 ^= x0;
    x0 += x1; x1 = rotl(x1, 29); x1 ^= x0;
    x0 += x1; x1 = rotl(x1, 16); x1 ^= x0;
    x0 += x1; x1 = rotl(x1, 24); x1 ^= x0;
    x0 += k1; x1 += k2 + 4u;
    x0 += x1; x1 = rotl(x1, 13); x1 ^= x0;
    x0 += x1; x1 = rotl(x1, 15); x1 ^= x0;
    x0 += x1; x1 = rotl(x1, 26); x1 ^= x0;
    x0 += x1; x1 = rotl(x1, 6);  x1 ^= x0;
    x0 += k2; x1 += k0 + 5u;
    o0 = x0; o1 = x1;
}

// XLA's f32 erf_inv (Giles polynomial)
__device__ __forceinline__ float erfinv_f(float x) {
    float w = -log1pf(-x * x);
    float p;
    if (w < 5.0f) {
        w = w - 2.5f;
        p = 2.81022636e-08f;
        p = fmaf(p, w, 3.43273939e-07f);
        p = fmaf(p, w, -3.5233877e-06f);
        p = fmaf(p, w, -4.39150654e-06f);
        p = fmaf(p, w, 0.00021858087f);
        p = fmaf(p, w, -0.00125372503f);
        p = fmaf(p, w, -0.00417768164f);
        p = fmaf(p, w, 0.246640727f);
        p = fmaf(p, w, 1.50140941f);
    } else {
        w = sqrtf(w) - 3.0f;
        p = -0.000200214257f;
        p = fmaf(p, w, 0.000100950558f);
        p = fmaf(p, w, 0.00134934322f);
        p = fmaf(p, w, -0.00367342844f);
        p = fmaf(p, w, 0.00573950773f);
        p = fmaf(p, w, -0.0076224613f);
        p = fmaf(p, w, 0.00943887047f);
        p = fmaf(p, w, 1.00167406f);
        p = fmaf(p, w, 2.83297682f);
    }
    return p * x;
}

__device__ __forceinline__ float noise_val(unsigned j, unsigned fk0, unsigned fk1) {
    unsigned i = (j < HALF) ? j : (j - HALF);
    unsigned o0, o1;
    tf2x32(fk0, fk1, i, i + HALF, o0, o1);
    unsigned bits = (j < HALF) ? o0 : o1;
    unsigned fb = (bits >> 9) | 0x3F800000u;
    float f = __uint_as_float(fb) - 1.0f;
    const float lo = -0.99999994f;
    float u = f * 2.0f + lo;
    u = fmaxf(lo, u);
    return 1.4142135381698608f * erfinv_f(u);
}

// f32 -> bf16 round-to-nearest-even
__device__ __forceinline__ ushort f2bf(float f) {
    unsigned u = __float_as_uint(f);
    unsigned r = (u + 0x7FFFu + ((u >> 16) & 1u)) >> 16;
    return (ushort)r;
}

// pack two f32 -> two bf16 in one dword (RNE), gfx950
__device__ __forceinline__ unsigned cvtpk(float lo, float hi) {
    unsigned r;
    asm volatile("v_cvt_pk_bf16_f32 %0, %1, %2" : "=v"(r) : "v"(lo), "v"(hi));
    return r;
}

// full-row swizzle: folds row bits 0-3 AND 4-7 into the 16B-chunk index.
__device__ __forceinline__ unsigned rsw(int row) {
    return ((unsigned)((row ^ (row >> 4)) & 15)) << 4;
}

// ---------------- FiLM params: film[b][{g1,b1,g2,b2}][HID] ----------------
__global__ void film_kernel(const int* __restrict__ cond,
                            const float* __restrict__ embed,
                            const float* __restrict__ f1w, const float* __restrict__ f1b,
                            const float* __restrict__ f2w, const float* __restrict__ f2b,
                            float* __restrict__ film) {
    int b = blockIdx.x;
    int j = threadIdx.x;  // 0..255
    __shared__ float emb[CDIM];
    if (j < CDIM) emb[j] = embed[(size_t)cond[b] * CDIM + j];
    __syncthreads();
    float a1 = f1b[j], a2 = f2b[j];
    for (int c = 0; c < CDIM; ++c) {
        float e = emb[c];
        a1 += e * f1w[c * 2 * HID + j];
        a2 += e * f2w[c * 2 * HID + j];
    }
    int which = j >> 7;
    int idx = j & 127;
    float* fb_ = film + (size_t)b * 4 * HID;
    fb_[which * HID + idx] = a1;
    fb_[(2 + which) * HID + idx] = a2;
}

// ------------- weights -> bf16, transposed to [out][in] (linear) -------------
__global__ void prep_weights(const float* __restrict__ fc1w,
                             const float* __restrict__ fc2w,
                             const float* __restrict__ fc3w,
                             ushort* __restrict__ w1t, ushort* __restrict__ w2t,
                             ushort* __restrict__ w3t) {
    int i = blockIdx.x * 256 + threadIdx.x;
    if (i < 128 * 64) {                       // w1t[j][k], k padded 52->64
        int j = i >> 6, k = i & 63;
        w1t[i] = (k < 52) ? f2bf(fc1w[k * HID + j]) : (ushort)0;
    } else if (i < 8192 + 128 * 128) {        // w2t[j][k]
        int m = i - 8192;
        int j = m >> 7, k = m & 127;
        w2t[m] = f2bf(fc2w[k * HID + j]);
    } else if (i < 8192 + 16384 + 16 * 128) { // w3t[c][k]
        int m = i - 24576;
        int c = m >> 7, k = m & 127;
        w3t[m] = f2bf(fc3w[k * Cc + c]);
    }
}

// ---------------- main MFMA kernel: 1 block = 1 image row (R18 config, best) ----------------
// 256 threads (4 waves), each wave owns 4 pixel-tiles (64 px). LDS 64 KB.
// XCD swizzle: physical blocks on one XCD cover CONSECUTIVE y rows, so the
// sobel halo rows (each x row read by blocks y-1,y,y+1) are XCD-L2-hot.
// feats: all 12 float4 loads issued first, threefry under them; ep3 x prefetch.
__global__ __launch_bounds__(256, 2)
void nca_mfma(const float* __restrict__ x,
              const ushort* __restrict__ w1t, const ushort* __restrict__ w2t,
              const ushort* __restrict__ w3t,
              const float* __restrict__ fc1b, const float* __restrict__ fc2b,
              const float* __restrict__ fc3b, const float* __restrict__ film,
              float* __restrict__ out, unsigned fk0, unsigned fk1) {
    __shared__ __align__(16) unsigned char Hb[256 * 256];   // 64 KB

    // XCD-aware remap: dispatch round-robins physical id P over 8 XCDs;
    // V = (P%8)*512 + P/8 gives each XCD a contiguous 512-row span. Bijective
    // (nwg = 4096 = 8*512). Mapping is a permutation -> correctness unaffected.
    const int P = blockIdx.x;
    const int blk = ((P & 7) << 9) | (P >> 3);
    const int b = blk >> 8, y = blk & 255;
    const int t = threadIdx.x;
    const float* xb = x + (size_t)b * Cc * Hh * Ww;

    // ---------- feats phase: thread = (px-quad q, ch-quad cq) ----------
    {
        const int q  = t & 63;        // lane: px 4q..4q+3
        const int cq = t >> 6;        // wave: channels 4cq..4cq+3
        const int px0 = q * 4;
        const bool okm = (y > 0), okp = (y < Hh - 1);
        const bool ql = (q > 0), qr = (q < 63);
        const float4 fz = {0.f, 0.f, 0.f, 0.f};

        // (1) issue all 12 global loads up front
        float4 RM[4], RC[4], RP[4];
        #pragma unroll
        for (int cc = 0; cc < 4; ++cc) {
            const int c = cq * 4 + cc;
            const float* base = xb + ((size_t)c * Hh + (size_t)y) * Ww + px0;
            RM[cc] = okm ? *(const float4*)(base - Ww) : fz;
            RC[cc] = *(const float4*)(base);
            RP[cc] = okp ? *(const float4*)(base + Ww) : fz;
        }

        // (2) threefry + erfinv while the loads are in flight (pure VALU)
        ushort nzs[4];
        {
            unsigned nbase = (((unsigned)(b * NOISEC + cq) * Hh + (unsigned)y) * Ww)
                             + (unsigned)px0;
            #pragma unroll
            for (int i = 0; i < 4; ++i)
                nzs[i] = f2bf(noise_val(nbase + (unsigned)i, fk0, fk1));
        }
        // write noise (independent of x loads)
        #pragma unroll
        for (int i = 0; i < 4; ++i) {
            const int row = px0 + i;
            const unsigned sw = rsw(row);
            *(ushort*)(Hb + row * 256 + (((224u ^ sw) + 2u * cq))) = nzs[i];
        }
        if (cq == 0) {
            #pragma unroll
            for (int i = 0; i < 4; ++i) {
                const int row = px0 + i;
                const unsigned sw = rsw(row);
                *(uint2*)(Hb + row * 256 + ((232u & 15u) + (224u ^ sw))) = (uint2){0u, 0u};
                *(uint4*)(Hb + row * 256 + (240u ^ sw)) = (uint4){0u, 0u, 0u, 0u};
            }
        }

        // (3) consume loads: shuffle halo, sobel, pack, LDS writes
        float vx[4][4], vgx[4][4], vgy[4][4];
        #pragma unroll
        for (int cc = 0; cc < 4; ++cc) {
            float4 rm = RM[cc], rc = RC[cc], rp = RP[cc];
            float mL = __shfl_up(rm.w, 1),  mR = __shfl_down(rm.x, 1);
            float cL = __shfl_up(rc.w, 1),  cR = __shfl_down(rc.x, 1);
            float pL = __shfl_up(rp.w, 1),  pR = __shfl_down(rp.x, 1);
            if (!ql) { mL = 0.f; cL = 0.f; pL = 0.f; }
            if (!qr) { mR = 0.f; cR = 0.f; pR = 0.f; }
            float am[6] = {mL, rm.x, rm.y, rm.z, rm.w, mR};
            float ac[6] = {cL, rc.x, rc.y, rc.z, rc.w, cR};
            float ap[6] = {pL, rp.x, rp.y, rp.z, rp.w, pR};
            #pragma unroll
            for (int i = 0; i < 4; ++i) {
                float a0 = am[i], a1 = am[i + 1], a2 = am[i + 2];
                float b0 = ac[i], b1 = ac[i + 1], b2 = ac[i + 2];
                float e0 = ap[i], e1 = ap[i + 1], e2 = ap[i + 2];
                vx[cc][i]  = b1;
                vgx[cc][i] = (a2 + 2.f * b2 + e2) - (a0 + 2.f * b0 + e0);
                vgy[cc][i] = (e0 + 2.f * e1 + e2) - (a0 + 2.f * a1 + a2);
            }
        }
        #pragma unroll
        for (int i = 0; i < 4; ++i) {
            const int row = px0 + i;
            const unsigned sw = rsw(row);
            unsigned char* rowp = Hb + row * 256;
            uint2 u;
            u.x = cvtpk(vx[0][i], vx[1][i]);  u.y = cvtpk(vx[2][i], vx[3][i]);
            *(uint2*)(rowp + ((128u + 8u * cq) ^ sw)) = u;
            u.x = cvtpk(vgx[0][i], vgx[1][i]); u.y = cvtpk(vgx[2][i], vgx[3][i]);
            *(uint2*)(rowp + ((160u + 8u * cq) ^ sw)) = u;
            u.x = cvtpk(vgy[0][i], vgy[1][i]); u.y = cvtpk(vgy[2][i], vgy[3][i]);
            *(uint2*)(rowp + ((192u + 8u * cq) ^ sw)) = u;
        }
    }
    __syncthreads();

    // ---------- GEMM phase: wave wv owns tiles 4wv..4wv+3 ----------
    const int lane = t & 63, wv = t >> 6;
    const int q = lane >> 4, p = lane & 15;
    const int nt0 = wv * 4;

    unsigned swn[4];
    #pragma unroll
    for (int n = 0; n < 4; ++n) swn[n] = rsw((nt0 + n) * 16 + p);

    f32x4 acc[8][4];

    // ---------- GEMM1: h1^T[128][64px] = W1[128][64] x feats^T ----------
    #pragma unroll
    for (int m = 0; m < 8; ++m)
        #pragma unroll
        for (int n = 0; n < 4; ++n) acc[m][n] = (f32x4){0.f, 0.f, 0.f, 0.f};

    #pragma unroll
    for (int ks = 0; ks < 2; ++ks) {
        short8 Bf[4];
        #pragma unroll
        for (int n = 0; n < 4; ++n) {
            int row = (nt0 + n) * 16 + p;
            Bf[n] = *(const short8*)(Hb + row * 256 +
                                     (((unsigned)(128 + ks * 64 + q * 16)) ^ swn[n]));
        }
        #pragma unroll
        for (int m = 0; m < 8; ++m) {
            short8 Af = *(const short8*)((const unsigned char*)w1t +
                                         (m * 16 + p) * 128 + ks * 64 + q * 16);
            #pragma unroll
            for (int n = 0; n < 4; ++n)
                acc[m][n] = __builtin_amdgcn_mfma_f32_16x16x32_bf16(Af, Bf[n], acc[m][n], 0, 0, 0);
        }
    }
    // epilogue 1: bias, relu, FiLM1, pack -> h rows (overwrites feats region)
    const float* flm = film + (size_t)b * 4 * HID;
    #pragma unroll
    for (int m = 0; m < 8; ++m) {
        int j0 = m * 16 + q * 4;
        float4 cb = *(const float4*)(fc1b + j0);
        float4 G  = *(const float4*)(flm + 0 * HID + j0);
        float4 Be = *(const float4*)(flm + 1 * HID + j0);
        #pragma unroll
        for (int n = 0; n < 4; ++n) {
            int row = (nt0 + n) * 16 + p;
            f32x4 a = acc[m][n];
            float v0 = G.x * fmaxf(a[0] + cb.x, 0.f) + Be.x;
            float v1 = G.y * fmaxf(a[1] + cb.y, 0.f) + Be.y;
            float v2 = G.z * fmaxf(a[2] + cb.z, 0.f) + Be.z;
            float v3 = G.w * fmaxf(a[3] + cb.w, 0.f) + Be.w;
            uint2 u2; u2.x = cvtpk(v0, v1); u2.y = cvtpk(v2, v3);
            *(uint2*)(Hb + row * 256 + (((unsigned)(m * 32 + q * 8)) ^ swn[n])) = u2;
        }
    }

    // ---------- GEMM2: h2^T[128][64px] = W2[128][128] x h1^T ----------
    #pragma unroll
    for (int m = 0; m < 8; ++m)
        #pragma unroll
        for (int n = 0; n < 4; ++n) acc[m][n] = (f32x4){0.f, 0.f, 0.f, 0.f};

    #pragma unroll
    for (int ks = 0; ks < 4; ++ks) {
        short8 Bf[4];
        #pragma unroll
        for (int n = 0; n < 4; ++n) {
            int row = (nt0 + n) * 16 + p;
            Bf[n] = *(const short8*)(Hb + row * 256 +
                                     (((unsigned)(ks * 64 + q * 16)) ^ swn[n]));
        }
        #pragma unroll
        for (int m = 0; m < 8; ++m) {
            short8 Af = *(const short8*)((const unsigned char*)w2t +
                                         (m * 16 + p) * 256 + ks * 64 + q * 16);
            #pragma unroll
            for (int n = 0; n < 4; ++n)
                acc[m][n] = __builtin_amdgcn_mfma_f32_16x16x32_bf16(Af, Bf[n], acc[m][n], 0, 0, 0);
        }
    }
    // epilogue 2: bias, relu, FiLM2, pack -> h rows (in place)
    #pragma unroll
    for (int m = 0; m < 8; ++m) {
        int j0 = m * 16 + q * 4;
        float4 cb = *(const float4*)(fc2b + j0);
        float4 G  = *(const float4*)(flm + 2 * HID + j0);
        float4 Be = *(const float4*)(flm + 3 * HID + j0);
        #pragma unroll
        for (int n = 0; n < 4; ++n) {
            int row = (nt0 + n) * 16 + p;
            f32x4 a = acc[m][n];
            float v0 = G.x * fmaxf(a[0] + cb.x, 0.f) + Be.x;
            float v1 = G.y * fmaxf(a[1] + cb.y, 0.f) + Be.y;
            float v2 = G.z * fmaxf(a[2] + cb.z, 0.f) + Be.z;
            float v3 = G.w * fmaxf(a[3] + cb.w, 0.f) + Be.w;
            uint2 u2; u2.x = cvtpk(v0, v1); u2.y = cvtpk(v2, v3);
            *(uint2*)(Hb + row * 256 + (((unsigned)(m * 32 + q * 8)) ^ swn[n])) = u2;
        }
    }

    // ---------- prefetch ep3's xb reloads (hide under GEMM3) ----------
    float xpre[4][4];
    #pragma unroll
    for (int n = 0; n < 4; ++n) {
        int px = (nt0 + n) * 16 + p;
        #pragma unroll
        for (int r = 0; r < 4; ++r) {
            int c = q * 4 + r;
            xpre[n][r] = xb[(size_t)c * Hh * Ww + (size_t)y * Ww + px];
        }
    }

    // ---------- GEMM3: dx^T[16][64px] = W3[16][128] x h2^T ----------
    f32x4 a3[4];
    #pragma unroll
    for (int n = 0; n < 4; ++n) a3[n] = (f32x4){0.f, 0.f, 0.f, 0.f};

    #pragma unroll
    for (int ks = 0; ks < 4; ++ks) {
        short8 Af = *(const short8*)((const unsigned char*)w3t +
                                     p * 256 + ks * 64 + q * 16);
        #pragma unroll
        for (int n = 0; n < 4; ++n) {
            int row = (nt0 + n) * 16 + p;
            short8 Bf = *(const short8*)(Hb + row * 256 +
                                         (((unsigned)(ks * 64 + q * 16)) ^ swn[n]));
            a3[n] = __builtin_amdgcn_mfma_f32_16x16x32_bf16(Af, Bf, a3[n], 0, 0, 0);
        }
    }
    // epilogue 3: bias, clip, Euler step (x values prefetched)
    {
        float4 c3 = *(const float4*)(fc3b + q * 4);
        float c3a[4] = {c3.x, c3.y, c3.z, c3.w};
        float* ob = out + (size_t)b * Cc * Hh * Ww;
        #pragma unroll
        for (int n = 0; n < 4; ++n) {
            int px = (nt0 + n) * 16 + p;
            #pragma unroll
            for (int r = 0; r < 4; ++r) {
                int c = q * 4 + r;
                float dx = a3[n][r] + c3a[r];
                dx = fminf(fmaxf(dx, -10.0f), 10.0f);
                size_t off = (size_t)c * Hh * Ww + (size_t)y * Ww + px;
                ob[off] = xpre[n][r] + 0.1f * dx;
            }
        }
    }
}

extern "C" void kernel_launch(void* const* d_in, const int* in_sizes, int n_in,
                              void* d_out, int out_size, void* d_ws, size_t ws_size,
                              hipStream_t stream) {
    const float* x     = (const float*)d_in[0];
    const int*   cond  = (const int*)d_in[1];
    const float* embed = (const float*)d_in[2];
    const float* f1w   = (const float*)d_in[3];
    const float* f1b   = (const float*)d_in[4];
    const float* f2w   = (const float*)d_in[5];
    const float* f2b   = (const float*)d_in[6];
    const float* fc1w  = (const float*)d_in[7];
    const float* fc1b  = (const float*)d_in[8];
    const float* fc2w  = (const float*)d_in[9];
    const float* fc2b  = (const float*)d_in[10];
    const float* fc3w  = (const float*)d_in[11];
    const float* fc3b  = (const float*)d_in[12];
    float* out = (float*)d_out;

    // ws layout: film f32 [16][4][128] (32 KB) | w1t bf16 (16 KB) | w2t (32 KB) | w3t (4 KB)
    float*  film = (float*)d_ws;
    ushort* w1t  = (ushort*)((char*)d_ws + 32768);
    ushort* w2t  = (ushort*)((char*)d_ws + 32768 + 16384);
    ushort* w3t  = (ushort*)((char*)d_ws + 32768 + 16384 + 32768);

    unsigned fk0, fk1;
    tf2x32(0u, 1u, 0u, 0u, fk0, fk1);   // fold_in(key(1), 0)

    film_kernel<<<Bn, 256, 0, stream>>>(cond, embed, f1w, f1b, f2w, f2b, film);
    prep_weights<<<(8192 + 16384 + 2048 + 255) / 256, 256, 0, stream>>>(
        fc1w, fc2w, fc3w, w1t, w2t, w3t);
    nca_mfma<<<Bn * Hh, 256, 0, stream>>>(x, w1t, w2t, w3t, fc1b, fc2b, fc3b,
                                          film, out, fk0, fk1);
}